// Round 15
// baseline (65.185 us; speedup 1.0000x reference)
//
#include <hip/hip_runtime.h>

// Problem constants (fixed by the reference)
#define BB 4
#define NN 50000
#define GG 2
#define EE 500000
#define HH 64
#define RR 16

#define CVT (GG * NN)                    // one thread per (g,node): fp8 row packing
#define PREPB ((CVT + 255) / 256)        // 391 blocks

// Binning geometry
#define NTT   512                        // nodes per dst-tile
#define TILES 98                         // ceil(NN / NTT)
#define PBLK  128                        // pass-1 blocks per graph
#define EPB   ((EE + PBLK - 1) / PBLK)   // 3907 edges per pass-1 block
#define CAP   64                         // records per (block,tile); mean 40, +3.8 sigma; 256B/bin
#define OVF_MAX 8192                     // overflow list capacity (expect ~10)

typedef float f32x2 __attribute__((ext_vector_type(2)));

// ---------------------------------------------------------------------------
// fp8 helpers (OCP e4m3, hw convert on gfx950)
// ---------------------------------------------------------------------------
__device__ inline unsigned int pack4_fp8(float f0, float f1, float f2, float f3) {
    int w = 0;
    w = __builtin_amdgcn_cvt_pk_fp8_f32(f0, f1, w, false);  // bytes 0,1
    w = __builtin_amdgcn_cvt_pk_fp8_f32(f2, f3, w, true);   // bytes 2,3
    return (unsigned int)w;
}

__device__ inline float dot16_fp8(uint4 a, uint4 b) {
    const unsigned int* pa = &a.x;
    const unsigned int* pb = &b.x;
    float s = 0.f;
#pragma unroll
    for (int i = 0; i < 4; ++i) {
        f32x2 al = __builtin_amdgcn_cvt_pk_f32_fp8((int)pa[i], false);
        f32x2 ah = __builtin_amdgcn_cvt_pk_f32_fp8((int)pa[i], true);
        f32x2 bl = __builtin_amdgcn_cvt_pk_f32_fp8((int)pb[i], false);
        f32x2 bh = __builtin_amdgcn_cvt_pk_f32_fp8((int)pb[i], true);
        s = fmaf(al.x, bl.x, s);
        s = fmaf(al.y, bl.y, s);
        s = fmaf(ah.x, bh.x, s);
        s = fmaf(ah.y, bh.y, s);
    }
    return s;
}

__device__ inline unsigned int f32_to_bf16_rn(float x) {
    unsigned int u = __float_as_uint(x);
    return (u + 0x7FFFu + ((u >> 16) & 1u)) >> 16;   // x >= 0, never NaN here
}

// ---------------------------------------------------------------------------
// Kernel A: prep — ONLY the fp8 gate tables (16B/row, mask folded into u-row
// LSBs) + overflow-counter zero. No planes, no pw/pb (moved to pass 2).
// ---------------------------------------------------------------------------
__global__ __launch_bounds__(256) void prep_kernel(
    const float* __restrict__ pert_mask,
    const float* __restrict__ gu, const float* __restrict__ gv,
    uint4* __restrict__ guh, uint4* __restrict__ gvh,
    int* __restrict__ ovf_cnt)
{
    int t = blockIdx.x * 256 + threadIdx.x;
    if (t == 0) *ovf_cnt = 0;
    if (t < CVT) {                       // t == g*NN + n
        int n = (t >= NN) ? (t - NN) : t;
        const float4* us = (const float4*)(gu + (size_t)t * RR);
        const float4* vs = (const float4*)(gv + (size_t)t * RR);
        float4 a0 = us[0], a1 = us[1], a2 = us[2], a3 = us[3];
        uint4 ur;
        ur.x = pack4_fp8(a0.x, a0.y, a0.z, a0.w);
        ur.y = pack4_fp8(a1.x, a1.y, a1.z, a1.w);
        ur.z = pack4_fp8(a2.x, a2.y, a2.z, a2.w);
        ur.w = pack4_fp8(a3.x, a3.y, a3.z, a3.w);
        // fold pert-mask bits into LSBs of bytes 0..3 (mask is src-indexed)
        unsigned int mbits =
            ((pert_mask[0*NN + n] != 0.f) ? 0x1u        : 0u) |
            ((pert_mask[1*NN + n] != 0.f) ? 0x100u      : 0u) |
            ((pert_mask[2*NN + n] != 0.f) ? 0x10000u    : 0u) |
            ((pert_mask[3*NN + n] != 0.f) ? 0x1000000u  : 0u);
        ur.x = (ur.x & 0xFEFEFEFEu) | mbits;
        guh[t] = ur;
        float4 b0 = vs[0], b1 = vs[1], b2 = vs[2], b3 = vs[3];
        uint4 vr;
        vr.x = pack4_fp8(b0.x, b0.y, b0.z, b0.w);
        vr.y = pack4_fp8(b1.x, b1.y, b1.z, b1.w);
        vr.z = pack4_fp8(b2.x, b2.y, b2.z, b2.w);
        vr.w = pack4_fp8(b3.x, b3.y, b3.z, b3.w);
        gvh[t] = vr;
    }
}

// ---------------------------------------------------------------------------
// Pass 1: per-edge gate -> packed record {bf16(w)<<16 | mask<<9 | dst_local}
// into bins[g][tile][blk][0..CAP). Overflow (deterministic, ~10 records at
// CAP=64) goes EXACTLY to a compact global list. Block 0 zeroes `out`.
// ---------------------------------------------------------------------------
__device__ inline void emit_edge(
    uint4 ua, uint4 va, float w0, int d, int g,
    int* lcnt, unsigned int* __restrict__ bins, int blk,
    int* __restrict__ ovf_cnt, uint2* __restrict__ ovf)
{
    float dot = dot16_fp8(ua, va);
    float w = w0 / (1.f + __expf(-dot));    // weight * sigmoid(dot)
    unsigned int mb = (ua.x & 1u) | ((ua.x >> 7) & 2u) |
                      ((ua.x >> 14) & 4u) | ((ua.x >> 21) & 8u);
    int tt = d >> 9;               // dst tile (NTT = 512)
    int dl = d & (NTT - 1);        // local dst (9 bits)
    int pos = atomicAdd(&lcnt[tt], 1);
    if (pos < CAP) {
        unsigned int rec = (f32_to_bf16_rn(w) << 16) | (mb << 9) | (unsigned)dl;
        __builtin_nontemporal_store(
            rec, &bins[(((size_t)g * TILES + tt) * PBLK + blk) * CAP + pos]);
    } else {
        // exact overflow path (deterministic, ~10 records total)
        int idx = atomicAdd(ovf_cnt, 1);
        if (idx < OVF_MAX)
            ovf[idx] = make_uint2((unsigned)(g * NN + d) | (mb << 20),
                                  __float_as_uint(w));
    }
}

__global__ __launch_bounds__(256) void edge_bin_kernel(
    const int* __restrict__ esrc, const int* __restrict__ edst,
    const float* __restrict__ ewgt, const uint4* __restrict__ guh,
    const uint4* __restrict__ gvh,
    unsigned int* __restrict__ bins, int* __restrict__ counts,
    int* __restrict__ ovf_cnt, uint2* __restrict__ ovf,
    float* __restrict__ out)
{
    int g   = blockIdx.x & 1;
    int blk = blockIdx.x >> 1;
    __shared__ int lcnt[TILES];
    int tid = threadIdx.x;
    if (tid < TILES) lcnt[tid] = 0;
    if (blockIdx.x == 0 && tid < BB * HH) out[tid] = 0.f;   // zero output
    __syncthreads();

    int base   = blk * EPB;
    int nEdges = min(EPB, EE - base);
    size_t gbase = (size_t)g * EE + base;
    int gN = g * NN;
    for (int it = tid; it < nEdges; it += 512) {
        int itB = it + 256;
        bool hB = itB < nEdges;
        int itBc = hB ? itB : it;            // clamp: loads unconditional
        int   sA  = __builtin_nontemporal_load(esrc + gbase + it);
        int   dA  = __builtin_nontemporal_load(edst + gbase + it);
        float wA  = __builtin_nontemporal_load(ewgt + gbase + it);
        int   sB  = __builtin_nontemporal_load(esrc + gbase + itBc);
        int   dB  = __builtin_nontemporal_load(edst + gbase + itBc);
        float wB  = __builtin_nontemporal_load(ewgt + gbase + itBc);
        uint4 uA = guh[gN + sA];
        uint4 vA = gvh[gN + dA];
        uint4 uB = guh[gN + sB];
        uint4 vB = gvh[gN + dB];
        emit_edge(uA, vA, wA, dA, g, lcnt, bins, blk, ovf_cnt, ovf);
        if (hB) emit_edge(uB, vB, wB, dB, g, lcnt, bins, blk, ovf_cnt, ovf);
    }
    __syncthreads();
    if (tid < TILES)
        counts[((size_t)g * TILES + tid) * PBLK + blk] = min(lcnt[tid], CAP);
}

// ---------------------------------------------------------------------------
// Pass 2 (FUSED replay + node reduction): one block per (tile, graph).
// Planes zero-seeded in LDS (no global fallback planes). pw/pb/wts computed
// per block (trivial). Overflow list (usually empty) applied exactly.
// ---------------------------------------------------------------------------
#define P2T 1024

__global__ __launch_bounds__(P2T) void tile_node_kernel(
    const unsigned int* __restrict__ bins, const int* __restrict__ counts,
    const float* __restrict__ ctx, const float* __restrict__ lin_w,
    const float* __restrict__ lin_b, const float* __restrict__ post_w,
    const float* __restrict__ post_b, const float* __restrict__ mix_w,
    const float* __restrict__ mix_b,
    const int* __restrict__ ovf_cnt, const uint2* __restrict__ ovf,
    float* __restrict__ out)
{
    int t = blockIdx.x;      // tile
    int g = blockIdx.y;      // graph
    int n0 = t * NTT;
    int ncnt = min(NTT, NN - n0);
    __shared__ float ls[5][NTT];         // 10 KB
    __shared__ int   lcnts[PBLK];        // 512 B
    __shared__ float red[4][BB * HH];    // 4 KB
    __shared__ float lpw[HH], lpb[HH], lwt[BB];
    __shared__ int   s_ovfn;
    int tid = threadIdx.x;

    // zero planes in LDS
    for (int i = tid; i < 5 * NTT; i += P2T) ((float*)ls)[i] = 0.f;
    if (tid < PBLK)
        lcnts[tid] = __builtin_nontemporal_load(
            counts + ((size_t)g * TILES + t) * PBLK + tid);
    // per-block pw/pb (64 FMA per thread, post_w L2-cached across blocks)
    if (tid >= P2T - HH) {
        int h = tid - (P2T - HH);
        float a = 0.f, c = 0.f;
        for (int k = 0; k < HH; ++k) {
            float w = post_w[k * HH + h];
            a = fmaf(lin_w[k], w, a);
            c = fmaf(lin_b[k], w, c);
        }
        lpw[h] = a; lpb[h] = c;
    } else if (tid >= P2T - HH - BB) {
        int b = tid - (P2T - HH - BB);
        float l0 = mix_b[0], l1 = mix_b[1];
        for (int h = 0; h < HH; ++h) {
            float cv = ctx[b * HH + h];
            l0 = fmaf(cv, mix_w[h * GG + 0], l0);
            l1 = fmaf(cv, mix_w[h * GG + 1], l1);
        }
        float m = fmaxf(l0, l1);
        float e0 = __expf(l0 - m), e1 = __expf(l1 - m);
        lwt[b] = ((g == 0) ? e0 : e1) / (e0 + e1);
    } else if (tid == 0) {
        s_ovfn = min(*ovf_cnt, OVF_MAX);
    }
    __syncthreads();

    // replay: 16 waves, 8 bins each (cnt ~40 -> one 64-lane pass/bin)
    int wv = tid >> 6, ln = tid & 63;
    const unsigned int* bbase = bins + ((size_t)g * TILES + t) * PBLK * CAP;
    for (int bI = wv; bI < PBLK; bI += P2T / 64) {
        int cnt = lcnts[bI];
        const unsigned int* rp = bbase + (size_t)bI * CAP;
        for (int i = ln; i < cnt; i += 64) {
            unsigned int r = __builtin_nontemporal_load(rp + i);
            float w = __uint_as_float(r & 0xFFFF0000u);
            int d = r & (NTT - 1);
            unsigned int mb = (r >> 9) & 15u;
            atomicAdd(&ls[0][d], w);
            if (mb & 1u) atomicAdd(&ls[1][d], w);
            if (mb & 2u) atomicAdd(&ls[2][d], w);
            if (mb & 4u) atomicAdd(&ls[3][d], w);
            if (mb & 8u) atomicAdd(&ls[4][d], w);
        }
    }
    // apply overflow list (usually 0 records)
    for (int i = tid; i < s_ovfn; i += P2T) {
        uint2 r = ovf[i];
        int key = (int)(r.x & 0xFFFFFu);
        int lo = g * NN + n0;
        if (key >= lo && key < lo + ncnt) {
            int d = key - lo;
            unsigned int mb = (r.x >> 20) & 15u;
            float w = __uint_as_float(r.y);
            atomicAdd(&ls[0][d], w);
            if (mb & 1u) atomicAdd(&ls[1][d], w);
            if (mb & 2u) atomicAdd(&ls[2][d], w);
            if (mb & 4u) atomicAdd(&ls[3][d], w);
            if (mb & 8u) atomicAdd(&ls[4][d], w);
        }
    }
    __syncthreads();

    // fused relu + partial-mean: (b, sub) wave-groups, h = lane
    int b   = (tid >> 6) & 3;
    int sub = tid >> 8;                  // 0..3
    int h   = tid & 63;
    float pwh = lpw[h], pbh = lpb[h], bias = post_b[h];
    float acc = 0.f;
    int i0 = sub * (NTT / 4);
    int i1 = min(i0 + (NTT / 4), ncnt);
    for (int i = i0; i < i1; ++i) {
        float x = fmaf(ls[1 + b][i], pwh, fmaf(ls[0][i], pbh, bias));
        acc += fmaxf(x, 0.f);
    }
    red[sub][b * HH + h] = acc;
    __syncthreads();
    if (tid < BB * HH) {
        float s = red[0][tid] + red[1][tid] + red[2][tid] + red[3][tid];
        int bb = tid >> 6;
        atomicAdd(&out[tid], s * lwt[bb] * (1.0f / NN));
    }
}

// ---------------------------------------------------------------------------
extern "C" void kernel_launch(void* const* d_in, const int* in_sizes, int n_in,
                              void* d_out, int out_size, void* d_ws, size_t ws_size,
                              hipStream_t stream) {
    const float* pert_mask = (const float*)d_in[0];
    const float* ctx       = (const float*)d_in[1];
    const int*   esrc      = (const int*)d_in[2];
    const int*   edst      = (const int*)d_in[3];
    const float* ewgt      = (const float*)d_in[4];
    const float* gu        = (const float*)d_in[5];
    const float* gv        = (const float*)d_in[6];
    const float* lin_w     = (const float*)d_in[7];
    const float* lin_b     = (const float*)d_in[8];
    const float* post_w    = (const float*)d_in[9];
    const float* post_b    = (const float*)d_in[10];
    const float* mix_w     = (const float*)d_in[11];
    const float* mix_b     = (const float*)d_in[12];
    float* out = (float*)d_out;

    // workspace layout (float units)
    float* ws = (float*)d_ws;
    uint4* guh = (uint4*)ws;                           // 100,000 uint4 = 400,000 f
    uint4* gvh = guh + 100000;                         // 400,000 f
    unsigned int* bins = (unsigned int*)(ws + 800000); // G*T*PBLK*CAP = 1,605,632 u32
    int* counts = (int*)(bins + (size_t)GG * TILES * PBLK * CAP);  // 25,088 int
    int* ovf_cnt = counts + GG * TILES * PBLK;         // 1 int (+1 pad)
    uint2* ovf = (uint2*)(ovf_cnt + 2);                // 8192 uint2

    prep_kernel<<<PREPB, 256, 0, stream>>>(
        pert_mask, gu, gv, guh, gvh, ovf_cnt);

    edge_bin_kernel<<<2 * PBLK, 256, 0, stream>>>(
        esrc, edst, ewgt, guh, gvh, bins, counts, ovf_cnt, ovf, out);

    dim3 tg(TILES, GG);
    tile_node_kernel<<<tg, P2T, 0, stream>>>(
        bins, counts, ctx, lin_w, lin_b, post_w, post_b, mix_w, mix_b,
        ovf_cnt, ovf, out);
}

// Round 16
// 56.395 us; speedup vs baseline: 1.1559x; 1.1559x over previous
//
#include <hip/hip_runtime.h>

// Problem constants (fixed by the reference)
#define BB 4
#define NN 50000
#define GG 2
#define EE 500000
#define HH 64
#define RR 16

#define CVT (GG * NN)                    // one thread per (g,node): fp8 row packing
#define PREPB ((CVT + 255) / 256)        // 391 blocks

// Binning geometry
#define NTT   512                        // nodes per dst-tile
#define TILES 98                         // ceil(NN / NTT)
#define PBLK  128                        // pass-1 blocks per graph
#define EPB   ((EE + PBLK - 1) / PBLK)   // 3907 edges per pass-1 block
#define CAP   64                         // records per (block,tile); mean 40, +3.8 sigma; 256B/bin
#define OVF_MAX 8192                     // overflow list capacity (expect ~10)

typedef float f32x2 __attribute__((ext_vector_type(2)));

// ---------------------------------------------------------------------------
// fp8 helpers (OCP e4m3, hw convert on gfx950)
// ---------------------------------------------------------------------------
__device__ inline unsigned int pack4_fp8(float f0, float f1, float f2, float f3) {
    int w = 0;
    w = __builtin_amdgcn_cvt_pk_fp8_f32(f0, f1, w, false);  // bytes 0,1
    w = __builtin_amdgcn_cvt_pk_fp8_f32(f2, f3, w, true);   // bytes 2,3
    return (unsigned int)w;
}

__device__ inline float dot16_fp8(uint4 a, uint4 b) {
    const unsigned int* pa = &a.x;
    const unsigned int* pb = &b.x;
    float s = 0.f;
#pragma unroll
    for (int i = 0; i < 4; ++i) {
        f32x2 al = __builtin_amdgcn_cvt_pk_f32_fp8((int)pa[i], false);
        f32x2 ah = __builtin_amdgcn_cvt_pk_f32_fp8((int)pa[i], true);
        f32x2 bl = __builtin_amdgcn_cvt_pk_f32_fp8((int)pb[i], false);
        f32x2 bh = __builtin_amdgcn_cvt_pk_f32_fp8((int)pb[i], true);
        s = fmaf(al.x, bl.x, s);
        s = fmaf(al.y, bl.y, s);
        s = fmaf(ah.x, bh.x, s);
        s = fmaf(ah.y, bh.y, s);
    }
    return s;
}

__device__ inline unsigned int f32_to_bf16_rn(float x) {
    unsigned int u = __float_as_uint(x);
    return (u + 0x7FFFu + ((u >> 16) & 1u)) >> 16;   // x >= 0, never NaN here
}

// ---------------------------------------------------------------------------
// Kernel A: prep — ONLY the fp8 gate tables (16B/row, mask folded into u-row
// LSBs) + overflow-counter zero. No planes, no pw/pb (moved to pass 2).
// ---------------------------------------------------------------------------
__global__ __launch_bounds__(256) void prep_kernel(
    const float* __restrict__ pert_mask,
    const float* __restrict__ gu, const float* __restrict__ gv,
    uint4* __restrict__ guh, uint4* __restrict__ gvh,
    int* __restrict__ ovf_cnt)
{
    int t = blockIdx.x * 256 + threadIdx.x;
    if (t == 0) *ovf_cnt = 0;
    if (t < CVT) {                       // t == g*NN + n
        int n = (t >= NN) ? (t - NN) : t;
        const float4* us = (const float4*)(gu + (size_t)t * RR);
        const float4* vs = (const float4*)(gv + (size_t)t * RR);
        float4 a0 = us[0], a1 = us[1], a2 = us[2], a3 = us[3];
        uint4 ur;
        ur.x = pack4_fp8(a0.x, a0.y, a0.z, a0.w);
        ur.y = pack4_fp8(a1.x, a1.y, a1.z, a1.w);
        ur.z = pack4_fp8(a2.x, a2.y, a2.z, a2.w);
        ur.w = pack4_fp8(a3.x, a3.y, a3.z, a3.w);
        // fold pert-mask bits into LSBs of bytes 0..3 (mask is src-indexed)
        unsigned int mbits =
            ((pert_mask[0*NN + n] != 0.f) ? 0x1u        : 0u) |
            ((pert_mask[1*NN + n] != 0.f) ? 0x100u      : 0u) |
            ((pert_mask[2*NN + n] != 0.f) ? 0x10000u    : 0u) |
            ((pert_mask[3*NN + n] != 0.f) ? 0x1000000u  : 0u);
        ur.x = (ur.x & 0xFEFEFEFEu) | mbits;
        guh[t] = ur;
        float4 b0 = vs[0], b1 = vs[1], b2 = vs[2], b3 = vs[3];
        uint4 vr;
        vr.x = pack4_fp8(b0.x, b0.y, b0.z, b0.w);
        vr.y = pack4_fp8(b1.x, b1.y, b1.z, b1.w);
        vr.z = pack4_fp8(b2.x, b2.y, b2.z, b2.w);
        vr.w = pack4_fp8(b3.x, b3.y, b3.z, b3.w);
        gvh[t] = vr;
    }
}

// ---------------------------------------------------------------------------
// Pass 1: per-edge gate -> packed record {bf16(w)<<16 | mask<<9 | dst_local}
// into bins[g][tile][blk][0..CAP) via NORMAL stores (L2-cached: pass 2 reads
// them back; NT store here cost +11 us in r15). Overflow (deterministic,
// ~10 records at CAP=64) goes EXACTLY to a compact global list.
// ---------------------------------------------------------------------------
__device__ inline void emit_edge(
    uint4 ua, uint4 va, float w0, int d, int g,
    int* lcnt, unsigned int* __restrict__ bins, int blk,
    int* __restrict__ ovf_cnt, uint2* __restrict__ ovf)
{
    float dot = dot16_fp8(ua, va);
    float w = w0 / (1.f + __expf(-dot));    // weight * sigmoid(dot)
    unsigned int mb = (ua.x & 1u) | ((ua.x >> 7) & 2u) |
                      ((ua.x >> 14) & 4u) | ((ua.x >> 21) & 8u);
    int tt = d >> 9;               // dst tile (NTT = 512)
    int dl = d & (NTT - 1);        // local dst (9 bits)
    int pos = atomicAdd(&lcnt[tt], 1);
    if (pos < CAP) {
        unsigned int rec = (f32_to_bf16_rn(w) << 16) | (mb << 9) | (unsigned)dl;
        bins[(((size_t)g * TILES + tt) * PBLK + blk) * CAP + pos] = rec;
    } else {
        // exact overflow path (deterministic, ~10 records total)
        int idx = atomicAdd(ovf_cnt, 1);
        if (idx < OVF_MAX)
            ovf[idx] = make_uint2((unsigned)(g * NN + d) | (mb << 20),
                                  __float_as_uint(w));
    }
}

__global__ __launch_bounds__(256) void edge_bin_kernel(
    const int* __restrict__ esrc, const int* __restrict__ edst,
    const float* __restrict__ ewgt, const uint4* __restrict__ guh,
    const uint4* __restrict__ gvh,
    unsigned int* __restrict__ bins, int* __restrict__ counts,
    int* __restrict__ ovf_cnt, uint2* __restrict__ ovf,
    float* __restrict__ out)
{
    int g   = blockIdx.x & 1;
    int blk = blockIdx.x >> 1;
    __shared__ int lcnt[TILES];
    int tid = threadIdx.x;
    if (tid < TILES) lcnt[tid] = 0;
    if (blockIdx.x == 0 && tid < BB * HH) out[tid] = 0.f;   // zero output
    __syncthreads();

    int base   = blk * EPB;
    int nEdges = min(EPB, EE - base);
    size_t gbase = (size_t)g * EE + base;
    int gN = g * NN;
    for (int it = tid; it < nEdges; it += 512) {
        int itB = it + 256;
        bool hB = itB < nEdges;
        int itBc = hB ? itB : it;            // clamp: loads unconditional
        int   sA  = __builtin_nontemporal_load(esrc + gbase + it);
        int   dA  = __builtin_nontemporal_load(edst + gbase + it);
        float wA  = __builtin_nontemporal_load(ewgt + gbase + it);
        int   sB  = __builtin_nontemporal_load(esrc + gbase + itBc);
        int   dB  = __builtin_nontemporal_load(edst + gbase + itBc);
        float wB  = __builtin_nontemporal_load(ewgt + gbase + itBc);
        uint4 uA = guh[gN + sA];
        uint4 vA = gvh[gN + dA];
        uint4 uB = guh[gN + sB];
        uint4 vB = gvh[gN + dB];
        emit_edge(uA, vA, wA, dA, g, lcnt, bins, blk, ovf_cnt, ovf);
        if (hB) emit_edge(uB, vB, wB, dB, g, lcnt, bins, blk, ovf_cnt, ovf);
    }
    __syncthreads();
    if (tid < TILES)
        counts[((size_t)g * TILES + tid) * PBLK + blk] = min(lcnt[tid], CAP);
}

// ---------------------------------------------------------------------------
// Pass 2 (FUSED replay + node reduction): one block per (tile, graph).
// Planes zero-seeded in LDS (no global fallback planes). pw/pb/wts computed
// per block (trivial). Overflow list (usually empty) applied exactly.
// ---------------------------------------------------------------------------
#define P2T 1024

__global__ __launch_bounds__(P2T) void tile_node_kernel(
    const unsigned int* __restrict__ bins, const int* __restrict__ counts,
    const float* __restrict__ ctx, const float* __restrict__ lin_w,
    const float* __restrict__ lin_b, const float* __restrict__ post_w,
    const float* __restrict__ post_b, const float* __restrict__ mix_w,
    const float* __restrict__ mix_b,
    const int* __restrict__ ovf_cnt, const uint2* __restrict__ ovf,
    float* __restrict__ out)
{
    int t = blockIdx.x;      // tile
    int g = blockIdx.y;      // graph
    int n0 = t * NTT;
    int ncnt = min(NTT, NN - n0);
    __shared__ float ls[5][NTT];         // 10 KB
    __shared__ int   lcnts[PBLK];        // 512 B
    __shared__ float red[4][BB * HH];    // 4 KB
    __shared__ float lpw[HH], lpb[HH], lwt[BB];
    __shared__ int   s_ovfn;
    int tid = threadIdx.x;

    // zero planes in LDS
    for (int i = tid; i < 5 * NTT; i += P2T) ((float*)ls)[i] = 0.f;
    if (tid < PBLK)
        lcnts[tid] = __builtin_nontemporal_load(
            counts + ((size_t)g * TILES + t) * PBLK + tid);
    // per-block pw/pb (64 FMA per thread, post_w L2-cached across blocks)
    if (tid >= P2T - HH) {
        int h = tid - (P2T - HH);
        float a = 0.f, c = 0.f;
        for (int k = 0; k < HH; ++k) {
            float w = post_w[k * HH + h];
            a = fmaf(lin_w[k], w, a);
            c = fmaf(lin_b[k], w, c);
        }
        lpw[h] = a; lpb[h] = c;
    } else if (tid >= P2T - HH - BB) {
        int b = tid - (P2T - HH - BB);
        float l0 = mix_b[0], l1 = mix_b[1];
        for (int h = 0; h < HH; ++h) {
            float cv = ctx[b * HH + h];
            l0 = fmaf(cv, mix_w[h * GG + 0], l0);
            l1 = fmaf(cv, mix_w[h * GG + 1], l1);
        }
        float m = fmaxf(l0, l1);
        float e0 = __expf(l0 - m), e1 = __expf(l1 - m);
        lwt[b] = ((g == 0) ? e0 : e1) / (e0 + e1);
    } else if (tid == 0) {
        s_ovfn = min(*ovf_cnt, OVF_MAX);
    }
    __syncthreads();

    // replay: 16 waves, 8 bins each (cnt ~40 -> one 64-lane pass/bin)
    int wv = tid >> 6, ln = tid & 63;
    const unsigned int* bbase = bins + ((size_t)g * TILES + t) * PBLK * CAP;
    for (int bI = wv; bI < PBLK; bI += P2T / 64) {
        int cnt = lcnts[bI];
        const unsigned int* rp = bbase + (size_t)bI * CAP;
        for (int i = ln; i < cnt; i += 64) {
            unsigned int r = __builtin_nontemporal_load(rp + i);
            float w = __uint_as_float(r & 0xFFFF0000u);
            int d = r & (NTT - 1);
            unsigned int mb = (r >> 9) & 15u;
            atomicAdd(&ls[0][d], w);
            if (mb & 1u) atomicAdd(&ls[1][d], w);
            if (mb & 2u) atomicAdd(&ls[2][d], w);
            if (mb & 4u) atomicAdd(&ls[3][d], w);
            if (mb & 8u) atomicAdd(&ls[4][d], w);
        }
    }
    // apply overflow list (usually 0 records)
    for (int i = tid; i < s_ovfn; i += P2T) {
        uint2 r = ovf[i];
        int key = (int)(r.x & 0xFFFFFu);
        int lo = g * NN + n0;
        if (key >= lo && key < lo + ncnt) {
            int d = key - lo;
            unsigned int mb = (r.x >> 20) & 15u;
            float w = __uint_as_float(r.y);
            atomicAdd(&ls[0][d], w);
            if (mb & 1u) atomicAdd(&ls[1][d], w);
            if (mb & 2u) atomicAdd(&ls[2][d], w);
            if (mb & 4u) atomicAdd(&ls[3][d], w);
            if (mb & 8u) atomicAdd(&ls[4][d], w);
        }
    }
    __syncthreads();

    // fused relu + partial-mean: (b, sub) wave-groups, h = lane
    int b   = (tid >> 6) & 3;
    int sub = tid >> 8;                  // 0..3
    int h   = tid & 63;
    float pwh = lpw[h], pbh = lpb[h], bias = post_b[h];
    float acc = 0.f;
    int i0 = sub * (NTT / 4);
    int i1 = min(i0 + (NTT / 4), ncnt);
    for (int i = i0; i < i1; ++i) {
        float x = fmaf(ls[1 + b][i], pwh, fmaf(ls[0][i], pbh, bias));
        acc += fmaxf(x, 0.f);
    }
    red[sub][b * HH + h] = acc;
    __syncthreads();
    if (tid < BB * HH) {
        float s = red[0][tid] + red[1][tid] + red[2][tid] + red[3][tid];
        int bb = tid >> 6;
        atomicAdd(&out[tid], s * lwt[bb] * (1.0f / NN));
    }
}

// ---------------------------------------------------------------------------
extern "C" void kernel_launch(void* const* d_in, const int* in_sizes, int n_in,
                              void* d_out, int out_size, void* d_ws, size_t ws_size,
                              hipStream_t stream) {
    const float* pert_mask = (const float*)d_in[0];
    const float* ctx       = (const float*)d_in[1];
    const int*   esrc      = (const int*)d_in[2];
    const int*   edst      = (const int*)d_in[3];
    const float* ewgt      = (const float*)d_in[4];
    const float* gu        = (const float*)d_in[5];
    const float* gv        = (const float*)d_in[6];
    const float* lin_w     = (const float*)d_in[7];
    const float* lin_b     = (const float*)d_in[8];
    const float* post_w    = (const float*)d_in[9];
    const float* post_b    = (const float*)d_in[10];
    const float* mix_w     = (const float*)d_in[11];
    const float* mix_b     = (const float*)d_in[12];
    float* out = (float*)d_out;

    // workspace layout (float units)
    float* ws = (float*)d_ws;
    uint4* guh = (uint4*)ws;                           // 100,000 uint4 = 400,000 f
    uint4* gvh = guh + 100000;                         // 400,000 f
    unsigned int* bins = (unsigned int*)(ws + 800000); // G*T*PBLK*CAP = 1,605,632 u32
    int* counts = (int*)(bins + (size_t)GG * TILES * PBLK * CAP);  // 25,088 int
    int* ovf_cnt = counts + GG * TILES * PBLK;         // 1 int (+1 pad)
    uint2* ovf = (uint2*)(ovf_cnt + 2);                // 8192 uint2

    prep_kernel<<<PREPB, 256, 0, stream>>>(
        pert_mask, gu, gv, guh, gvh, ovf_cnt);

    edge_bin_kernel<<<2 * PBLK, 256, 0, stream>>>(
        esrc, edst, ewgt, guh, gvh, bins, counts, ovf_cnt, ovf, out);

    dim3 tg(TILES, GG);
    tile_node_kernel<<<tg, P2T, 0, stream>>>(
        bins, counts, ctx, lin_w, lin_b, post_w, post_b, mix_w, mix_b,
        ovf_cnt, ovf, out);
}

// Round 18
// 50.233 us; speedup vs baseline: 1.2976x; 1.1227x over previous
//
#include <hip/hip_runtime.h>

// Problem constants (fixed by the reference)
#define BB 4
#define NN 50000
#define GG 2
#define EE 500000
#define HH 64
#define RR 16

#define CVT (GG * NN)                    // fp8 u-table rows
#define K1B 256                          // K1 blocks total (2 graphs x 128)
#define ROWS_PB ((CVT + K1B - 1) / K1B)  // 391 table rows per K1 block

// Binning geometry
#define NTT   512                        // nodes per dst-tile
#define TILES 98                         // ceil(NN / NTT)
#define PBLK  128                        // K1 blocks per graph
#define EPB   ((EE + PBLK - 1) / PBLK)   // 3907 edges per K1 block
#define CAP   64                         // records per (block,tile); mean 40, +3.8 sigma

typedef float f32x2 __attribute__((ext_vector_type(2)));

// ---------------------------------------------------------------------------
// fp8 helpers (OCP e4m3, hw convert on gfx950)
// ---------------------------------------------------------------------------
__device__ inline unsigned int pack4_fp8(float f0, float f1, float f2, float f3) {
    int w = 0;
    w = __builtin_amdgcn_cvt_pk_fp8_f32(f0, f1, w, false);  // bytes 0,1
    w = __builtin_amdgcn_cvt_pk_fp8_f32(f2, f3, w, true);   // bytes 2,3
    return (unsigned int)w;
}

// ---------------------------------------------------------------------------
// K1: u-table fp8 conversion (mask folded into LSBs of bytes 0..3) + edge
// binning of RAW records {src | dst<<16, ewgt_f32} by dst-tile. Per-block
// spill region sized EPB -> unconditional exactness, no global counters.
// Block 0 zeroes `out`.
// ---------------------------------------------------------------------------
__global__ __launch_bounds__(256) void prep_bin_kernel(
    const float* __restrict__ pert_mask, const float* __restrict__ gu,
    const int* __restrict__ esrc, const int* __restrict__ edst,
    const float* __restrict__ ewgt,
    uint4* __restrict__ guh, unsigned long long* __restrict__ bins,
    int* __restrict__ counts, unsigned long long* __restrict__ spill,
    int* __restrict__ scnt, float* __restrict__ out)
{
    int g   = blockIdx.x & 1;
    int blk = blockIdx.x >> 1;
    int tid = threadIdx.x;
    __shared__ int lcnt[TILES];
    __shared__ int lspill;
    if (tid < TILES) lcnt[tid] = 0;
    if (tid == 0) lspill = 0;
    if (blockIdx.x == 0 && tid < BB * HH) out[tid] = 0.f;
    __syncthreads();

    // --- u-table conversion slice (independent of edge slice) ---
    int r0 = blockIdx.x * ROWS_PB;
    int r1 = min(r0 + ROWS_PB, CVT);
    for (int r = r0 + tid; r < r1; r += 256) {
        int n = (r >= NN) ? (r - NN) : r;
        const float4* us = (const float4*)(gu + (size_t)r * RR);
        float4 a0 = us[0], a1 = us[1], a2 = us[2], a3 = us[3];
        uint4 ur;
        ur.x = pack4_fp8(a0.x, a0.y, a0.z, a0.w);
        ur.y = pack4_fp8(a1.x, a1.y, a1.z, a1.w);
        ur.z = pack4_fp8(a2.x, a2.y, a2.z, a2.w);
        ur.w = pack4_fp8(a3.x, a3.y, a3.z, a3.w);
        unsigned int mbits =
            ((pert_mask[0*NN + n] != 0.f) ? 0x1u        : 0u) |
            ((pert_mask[1*NN + n] != 0.f) ? 0x100u      : 0u) |
            ((pert_mask[2*NN + n] != 0.f) ? 0x10000u    : 0u) |
            ((pert_mask[3*NN + n] != 0.f) ? 0x1000000u  : 0u);
        ur.x = (ur.x & 0xFEFEFEFEu) | mbits;
        guh[r] = ur;
    }

    // --- edge binning (raw records; no gate math here) ---
    int base   = blk * EPB;
    int nE     = min(EPB, EE - base);
    size_t gb  = (size_t)g * EE + base;
    for (int it = tid; it < nE; it += 256) {
        int   s  = __builtin_nontemporal_load(esrc + gb + it);
        int   d  = __builtin_nontemporal_load(edst + gb + it);
        float w0 = __builtin_nontemporal_load(ewgt + gb + it);
        unsigned long long rec =
            (unsigned long long)((unsigned)s | ((unsigned)d << 16)) |
            ((unsigned long long)__float_as_uint(w0) << 32);
        int tt  = d >> 9;               // dst tile
        int pos = atomicAdd(&lcnt[tt], 1);
        if (pos < CAP) {
            bins[(((size_t)g * TILES + tt) * PBLK + blk) * CAP + pos] = rec;
        } else {
            int sp = atomicAdd(&lspill, 1);     // sp < nE <= EPB always
            spill[((size_t)g * PBLK + blk) * EPB + sp] = rec;
        }
    }
    __syncthreads();
    if (tid < TILES)
        counts[((size_t)g * TILES + tid) * PBLK + blk] = min(lcnt[tid], CAP);
    if (tid == 0) scnt[g * PBLK + blk] = lspill;
}

// ---------------------------------------------------------------------------
// K2: per (tile,g) block. v-tile loaded COALESCED from f32 gate_v into padded
// LDS [NTT][17] (conflict-light scalar reads). Replay records: u-gather (L2) +
// LDS-v dot + sigmoid, accumulate planes, then fused ReLU-mean + out atomics.
// ---------------------------------------------------------------------------
#define P2T 1024

__device__ inline void replay_rec(
    unsigned long long rec, int n0, int ncnt, int g,
    const uint4* __restrict__ guh, float (*vt)[RR + 1], float (*ls)[NTT],
    bool check_range)
{
    unsigned int key = (unsigned int)rec;
    int d = (int)(key >> 16);
    int dl = d - n0;
    if (check_range && ((unsigned)dl >= (unsigned)ncnt)) return;
    int s = key & 0xFFFFu;
    float w0 = __uint_as_float((unsigned int)(rec >> 32));
    uint4 u = guh[(size_t)g * NN + s];      // 16B gather, L2-resident
    const unsigned int* pu = &u.x;
    float dot = 0.f;
#pragma unroll
    for (int q = 0; q < 4; ++q) {
        f32x2 lo = __builtin_amdgcn_cvt_pk_f32_fp8((int)pu[q], false);
        f32x2 hi = __builtin_amdgcn_cvt_pk_f32_fp8((int)pu[q], true);
        dot = fmaf(lo.x, vt[dl][q * 4 + 0], dot);
        dot = fmaf(lo.y, vt[dl][q * 4 + 1], dot);
        dot = fmaf(hi.x, vt[dl][q * 4 + 2], dot);
        dot = fmaf(hi.y, vt[dl][q * 4 + 3], dot);
    }
    float w = w0 / (1.f + __expf(-dot));
    unsigned int mb = (u.x & 1u) | ((u.x >> 7) & 2u) |
                      ((u.x >> 14) & 4u) | ((u.x >> 21) & 8u);
    atomicAdd(&ls[0][dl], w);
    if (mb & 1u) atomicAdd(&ls[1][dl], w);
    if (mb & 2u) atomicAdd(&ls[2][dl], w);
    if (mb & 4u) atomicAdd(&ls[3][dl], w);
    if (mb & 8u) atomicAdd(&ls[4][dl], w);
}

__global__ __launch_bounds__(P2T) void tile_node_kernel(
    const uint4* __restrict__ guh, const unsigned long long* __restrict__ bins,
    const int* __restrict__ counts, const unsigned long long* __restrict__ spill,
    const int* __restrict__ scnt, const float* __restrict__ gv,
    const float* __restrict__ ctx, const float* __restrict__ lin_w,
    const float* __restrict__ lin_b, const float* __restrict__ post_w,
    const float* __restrict__ post_b, const float* __restrict__ mix_w,
    const float* __restrict__ mix_b, float* __restrict__ out)
{
    int t = blockIdx.x;      // tile
    int g = blockIdx.y;      // graph
    int n0 = t * NTT;
    int ncnt = min(NTT, NN - n0);
    __shared__ float vt[NTT][RR + 1];    // 34.8 KB, padded rows
    __shared__ float ls[5][NTT];         // 10 KB
    __shared__ int   lcnts[PBLK];        // 512 B
    __shared__ float red[4][BB * HH];    // 4 KB
    __shared__ float lpw[HH], lpb[HH], lwt[BB];
    int tid = threadIdx.x;

    // v-tile: coalesced float4 reads, scalar LDS stores into padded rows
    for (int i = tid; i < ncnt * 4; i += P2T) {
        int row = i >> 2, q = i & 3;
        float4 v = ((const float4*)(gv + ((size_t)g * NN + n0 + row) * RR))[q];
        vt[row][q * 4 + 0] = v.x;
        vt[row][q * 4 + 1] = v.y;
        vt[row][q * 4 + 2] = v.z;
        vt[row][q * 4 + 3] = v.w;
    }
    for (int i = tid; i < 5 * NTT; i += P2T) ((float*)ls)[i] = 0.f;
    if (tid < PBLK)
        lcnts[tid] = __builtin_nontemporal_load(
            counts + ((size_t)g * TILES + t) * PBLK + tid);
    if (tid >= P2T - HH) {
        int h = tid - (P2T - HH);
        float a = 0.f, c = 0.f;
        for (int k = 0; k < HH; ++k) {
            float w = post_w[k * HH + h];
            a = fmaf(lin_w[k], w, a);
            c = fmaf(lin_b[k], w, c);
        }
        lpw[h] = a; lpb[h] = c;
    } else if (tid >= P2T - HH - BB) {
        int b = tid - (P2T - HH - BB);
        float l0 = mix_b[0], l1 = mix_b[1];
        for (int h = 0; h < HH; ++h) {
            float cv = ctx[b * HH + h];
            l0 = fmaf(cv, mix_w[h * GG + 0], l0);
            l1 = fmaf(cv, mix_w[h * GG + 1], l1);
        }
        float m = fmaxf(l0, l1);
        float e0 = __expf(l0 - m), e1 = __expf(l1 - m);
        lwt[b] = ((g == 0) ? e0 : e1) / (e0 + e1);
    }
    __syncthreads();

    int wv = tid >> 6, ln = tid & 63;
    const unsigned long long* bbase =
        bins + ((size_t)g * TILES + t) * PBLK * CAP;

    // main replay: 16 waves, 8 bins each (cnt ~40 -> one 64-lane pass/bin)
    for (int bI = wv; bI < PBLK; bI += P2T / 64) {
        int cnt = lcnts[bI];
        const unsigned long long* rp = bbase + (size_t)bI * CAP;
        for (int i = ln; i < cnt; i += 64) {
            unsigned long long rec = __builtin_nontemporal_load(rp + i);
            replay_rec(rec, n0, ncnt, g, guh, vt, ls, false);
        }
    }
    // spill replay (statistically ~0 records; exactness guaranteed)
    for (int bI = wv; bI < PBLK; bI += P2T / 64) {
        int sc = scnt[g * PBLK + bI];
        const unsigned long long* rp = spill + ((size_t)g * PBLK + bI) * EPB;
        for (int i = ln; i < sc; i += 64) {
            unsigned long long rec = rp[i];
            replay_rec(rec, n0, ncnt, g, guh, vt, ls, true);
        }
    }
    __syncthreads();

    // fused relu + partial-mean: (b, sub) wave-groups, h = lane
    int b   = (tid >> 6) & 3;
    int sub = tid >> 8;                  // 0..3
    int h   = tid & 63;
    float pwh = lpw[h], pbh = lpb[h], bias = post_b[h];
    float acc = 0.f;
    int i0 = sub * (NTT / 4);
    int i1 = min(i0 + (NTT / 4), ncnt);
    for (int i = i0; i < i1; ++i) {
        float x = fmaf(ls[1 + b][i], pwh, fmaf(ls[0][i], pbh, bias));
        acc += fmaxf(x, 0.f);
    }
    red[sub][b * HH + h] = acc;
    __syncthreads();
    if (tid < BB * HH) {
        float s = red[0][tid] + red[1][tid] + red[2][tid] + red[3][tid];
        int bb = tid >> 6;
        atomicAdd(&out[tid], s * lwt[bb] * (1.0f / NN));
    }
}

// ---------------------------------------------------------------------------
extern "C" void kernel_launch(void* const* d_in, const int* in_sizes, int n_in,
                              void* d_out, int out_size, void* d_ws, size_t ws_size,
                              hipStream_t stream) {
    const float* pert_mask = (const float*)d_in[0];
    const float* ctx       = (const float*)d_in[1];
    const int*   esrc      = (const int*)d_in[2];
    const int*   edst      = (const int*)d_in[3];
    const float* ewgt      = (const float*)d_in[4];
    const float* gu        = (const float*)d_in[5];
    const float* gv        = (const float*)d_in[6];
    const float* lin_w     = (const float*)d_in[7];
    const float* lin_b     = (const float*)d_in[8];
    const float* post_w    = (const float*)d_in[9];
    const float* post_b    = (const float*)d_in[10];
    const float* mix_w     = (const float*)d_in[11];
    const float* mix_b     = (const float*)d_in[12];
    float* out = (float*)d_out;

    // workspace layout (float units; 8B-aligned regions for u64 records)
    float* ws = (float*)d_ws;
    uint4* guh = (uint4*)ws;                            // 100,000 uint4 -> 400,000 f
    unsigned long long* bins = (unsigned long long*)(ws + 400000);
                                                        // G*T*PBLK*CAP = 1,605,632 u64
    int* counts = (int*)(ws + 3611264);                 // 25,088 int
    int* scnt   = (int*)(ws + 3636352);                 // 256 int
    unsigned long long* spill = (unsigned long long*)(ws + 3636608);
                                                        // G*PBLK*EPB u64

    prep_bin_kernel<<<K1B, 256, 0, stream>>>(
        pert_mask, gu, esrc, edst, ewgt, guh, bins, counts, spill, scnt, out);

    dim3 tg(TILES, GG);
    tile_node_kernel<<<tg, P2T, 0, stream>>>(
        guh, bins, counts, spill, scnt, gv, ctx, lin_w, lin_b, post_w,
        post_b, mix_w, mix_b, out);
}